// Round 17
// baseline (32.703 us; speedup 1.0000x reference)
//
#include <hip/hip_runtime.h>
#include <hip/hip_bf16.h>
#include <hip/hip_fp16.h>

// Problem constants (fixed by the reference harness)
#define N_NODES 32768
#define N_EDGES 524288
#define NGRAPH  256
#define NPG     128
#define EPG     2048     // edges per graph (DEG=16)
#define F_IN    64
#define F1      128
#define F2      64
#define F3      32
#define TN      16
#define BINS    16

typedef _Float16 f16;
typedef _Float16 f16x4 __attribute__((ext_vector_type(4)));
typedef _Float16 f16x8 __attribute__((ext_vector_type(8)));
typedef float    f32x4 __attribute__((ext_vector_type(4)));

__device__ __forceinline__ float sigmoidf(float x) { return 1.f / (1.f + expf(-x)); }

// ---- LDS pool (bytes), 149504 total -> 1 block/CU, 16 waves ----
#define L_A    0        // Acnt u32[128][68] == Amat f16[128][136] (per side)
#define L_R1   34816    // xT[64][136] -> h1[128][136] -> h2[128][72]
#define L_R2   69632    // W1T[128][72]
#define L_R3   88064    // out1[128][72] -> t2T[64][136] -> t3T[32][136] -> post smalls
#define L_R4   106496   // W2T[64][136] -> lhist u8[17][1040] (spills into R5)
#define L_R5   123904   // W3T[32][72]
#define L_DT   128512   // dt f16[2][128][40]; dt_b area doubles as cnt4_b+dinvB pre-agg3_b
#define L_DINV 148992   // dinv f32[128] (side a)
#define POOLB  149504

#define SA  136   // Amat / xT / h1 / W2T / t2T / t3T stride (f16)
#define SB  72    // out1 / W1T / h2 / W3T stride
#define SD  40    // dt stride
#define LHS 1040  // lhist stride (bytes), 16B-aligned

// ---- generic MFMA matmul over LDS f16 tiles; 16 waves = 8 M-strips x 2 N-halves ----
// out[r][c] (or out[c][r] if TRANS) = sum_k A[r][k]*B^T[c][k] (+bias[c]) (relu)
template<int N, int K, int AS, int BS, int OS, bool TRANS, bool RELU>
__device__ __forceinline__ void mfma_mm(const f16* __restrict__ A,
                                        const f16* __restrict__ B,
                                        const float* __restrict__ bias,
                                        f16* __restrict__ out, int tid) {
    const int w = tid >> 6, lane = tid & 63;
    const int col = lane & 15, g = lane >> 4;
    const int strip = w & 7, nh = w >> 3;
    const int rowa = strip * 16 + col;
    constexpr int NT = N / 16, KS = K / 32, NT2 = NT / 2;
    f32x4 acc[NT2];
#pragma unroll
    for (int nt = 0; nt < NT2; ++nt) {
        const float b = bias ? bias[(nh * NT2 + nt) * 16 + col] : 0.f;
        acc[nt] = (f32x4){b, b, b, b};
    }
#pragma unroll
    for (int ks = 0; ks < KS; ++ks) {
        const f16x8 a = *(const f16x8*)&A[rowa * AS + ks * 32 + g * 8];
#pragma unroll
        for (int nt = 0; nt < NT2; ++nt) {
            const f16x8 b = *(const f16x8*)&B[((nh * NT2 + nt) * 16 + col) * BS + ks * 32 + g * 8];
            acc[nt] = __builtin_amdgcn_mfma_f32_16x16x32_f16(a, b, acc[nt], 0, 0, 0);
        }
    }
#pragma unroll
    for (int nt = 0; nt < NT2; ++nt) {
        const int c = (nh * NT2 + nt) * 16 + col;
        if (TRANS) {
            f16x4 o;
#pragma unroll
            for (int j = 0; j < 4; ++j) {
                float v = acc[nt][j];
                if (RELU) v = fmaxf(v, 0.f);
                o[j] = (f16)v;
            }
            *(f16x4*)&out[c * OS + strip * 16 + g * 4] = o;
        } else {
#pragma unroll
            for (int j = 0; j < 4; ++j) {
                float v = acc[nt][j];
                if (RELU) v = fmaxf(v, 0.f);
                out[(strip * 16 + g * 4 + j) * OS + c] = (f16)v;
            }
        }
    }
}

// ---- the whole network: one block per graph pair, one dispatch, 1024 threads ----
__global__ __launch_bounds__(1024, 4) void genn_all(
    const float* __restrict__ x1, const int* __restrict__ ei1,
    const float* __restrict__ x2, const int* __restrict__ ei2,
    const float* __restrict__ W1, const float* __restrict__ b1,
    const float* __restrict__ W2, const float* __restrict__ b2,
    const float* __restrict__ W3, const float* __restrict__ b3,
    const float* __restrict__ attW, const float* __restrict__ tW,
    const float* __restrict__ tblk, const float* __restrict__ tbias,
    const float* __restrict__ sW1, const float* __restrict__ sb1,
    const float* __restrict__ sW2, const float* __restrict__ sb2,
    float* __restrict__ outp) {
    __shared__ __align__(16) char pool[POOLB];
    unsigned int* Acnt = (unsigned int*)(pool + L_A);
    f16*   Amat = (f16*)(pool + L_A);
    f16*   dts  = (f16*)(pool + L_DT);
    float* dinv = (float*)(pool + L_DINV);
    // side-b setup state parked in the dt_b region (dt_b written only at agg3_b)
    unsigned int* cnt4  = (unsigned int*)(pool + L_DT + 10240);   // u4 [128][128] = 8192 B
    float*        dinvB = (float*)(pool + L_DT + 18432);          // 512 B

    const int g = blockIdx.x;
    const int tid = threadIdx.x;
    const int wv = tid >> 6, lane = tid & 63;
    const int nb = g * NPG;

    // ---- P0: zero Acnt (2176 uint4) + cnt4 (512 uint4) ----
    for (int i = tid; i < 2176; i += 1024)
        ((uint4*)Acnt)[i] = make_uint4(0, 0, 0, 0);
    if (tid < 512) ((uint4*)cnt4)[tid] = make_uint4(0, 0, 0, 0);
    __syncthreads();

    // ---- P1: scatter BOTH sides + stage x1T + stage all W's ----
#pragma unroll
    for (int it = 0; it < 2; ++it) {
        const int e = it * 1024 + tid;
        const int d = ei1[N_EDGES + (size_t)g * EPG + e] - nb;
        const int s = ei1[(size_t)g * EPG + e] - nb;
        atomicAdd(&Acnt[d * 68 + (s >> 1)], 1u << ((s & 1) << 4));
    }
#pragma unroll
    for (int it = 0; it < 2; ++it) {
        const int e = it * 1024 + tid;
        const int d = ei2[N_EDGES + (size_t)g * EPG + e] - nb;
        const int s = ei2[(size_t)g * EPG + e] - nb;
        atomicAdd(&cnt4[d * 16 + (s >> 3)], 1u << ((s & 7) << 2));
    }
    {
        const float* xg = x1 + (size_t)g * NPG * F_IN;
        f16* xT = (f16*)(pool + L_R1);
#pragma unroll
        for (int it = 0; it < 2; ++it) {
            const int idx = (it * 1024 + tid) * 4;
            const float4 v = *(const float4*)&xg[idx];
            const int n = idx >> 6, c = idx & 63;
            xT[(c + 0) * SA + n] = (f16)v.x;
            xT[(c + 1) * SA + n] = (f16)v.y;
            xT[(c + 2) * SA + n] = (f16)v.z;
            xT[(c + 3) * SA + n] = (f16)v.w;
        }
        f16* W1T = (f16*)(pool + L_R2);
        for (int i = tid; i < F_IN * F1; i += 1024)
            W1T[(i & 127) * SB + (i >> 7)] = (f16)W1[i];
        f16* W2T = (f16*)(pool + L_R4);
        for (int i = tid; i < F1 * F2; i += 1024)
            W2T[(i & 63) * SA + (i >> 6)] = (f16)W2[i];
        f16* W3T = (f16*)(pool + L_R5);
        for (int i = tid; i < F2 * F3; i += 1024)
            W3T[(i & 31) * SB + (i >> 5)] = (f16)W3[i];
    }
    __syncthreads();

    // ---- P2: rowsums for BOTH sides ----
    if (tid < 512) {
        const int d = tid >> 2, q = tid & 3;
        unsigned int s = 0;
        const unsigned int* rp = &Acnt[d * 68 + q * 17];
        for (int j = 0; j < 17; ++j) {
            const unsigned int v = rp[j];
            s += (v & 0xffffu) + (v >> 16);
        }
        s += __shfl_down((int)s, 2);
        s += __shfl_down((int)s, 1);
        if (q == 0) dinv[d] = rsqrtf((float)s + 1.0f);
    } else {
        const int t = tid - 512;
        const int d = t >> 2, q = t & 3;
        unsigned int s = 0;
#pragma unroll
        for (int k = 0; k < 4; ++k) {
            const unsigned int v = cnt4[d * 16 + q * 4 + k];
            const unsigned int v2 = (v & 0x0F0F0F0Fu) + ((v >> 4) & 0x0F0F0F0Fu);
            s += (v2 & 0xFFu) + ((v2 >> 8) & 0xFFu) + ((v2 >> 16) & 0xFFu) + (v2 >> 24);
        }
        s += __shfl_down((int)s, 2);
        s += __shfl_down((int)s, 1);
        if (q == 0) dinvB[d] = rsqrtf((float)s + 1.0f);
    }
    __syncthreads();

    // ---- P3: convert side-a counts -> Amat f16 in place (+ self loop) ----
    for (int i = tid; i < 8704; i += 1024) {
        const int d = i / 68, w = i % 68;
        const unsigned int v = Acnt[i];
        const int s0 = 2 * w, s1 = 2 * w + 1;
        int c0 = v & 0xffffu, c1 = v >> 16;
        if (s0 == d) ++c0;
        if (s1 == d) ++c1;
        const float dd = dinv[d];
        const f16 f0 = (f16)((float)c0 * dinv[s0 & 127] * dd);
        const f16 f1 = (f16)((float)c1 * dinv[s1 & 127] * dd);
        unsigned short u0 = __builtin_bit_cast(unsigned short, f0);
        unsigned short u1 = __builtin_bit_cast(unsigned short, f1);
        Acnt[i] = (unsigned int)u0 | ((unsigned int)u1 << 16);
    }
    __syncthreads();

    // ---- region aliases ----
    f16* xT   = (f16*)(pool + L_R1);
    f16* h1   = (f16*)(pool + L_R1);
    f16* h2   = (f16*)(pool + L_R1);   // reuses R1 (h1 dead after mm2)
    f16* W1T  = (f16*)(pool + L_R2);
    f16* out1 = (f16*)(pool + L_R3);
    f16* t2T  = (f16*)(pool + L_R3);
    f16* t3T  = (f16*)(pool + L_R3);
    f16* W2T  = (f16*)(pool + L_R4);
    f16* W3T  = (f16*)(pool + L_R5);

    // ---- side 0 layers ----
    mfma_mm<64, 128, SA, SA, SB, false, false>(Amat, xT, nullptr, out1, tid);  // agg1
    __syncthreads();
    mfma_mm<128, 64, SB, SB, SA, false, true>(out1, W1T, b1, h1, tid);         // mm1
    __syncthreads();
    mfma_mm<64, 128, SA, SA, SA, true, false>(h1, W2T, nullptr, t2T, tid);     // mm2 (T)
    __syncthreads();
    mfma_mm<64, 128, SA, SA, SB, false, true>(Amat, t2T, b2, h2, tid);         // agg2
    __syncthreads();
    mfma_mm<32, 64, SB, SB, SA, true, false>(h2, W3T, nullptr, t3T, tid);      // mm3 (T)
    __syncthreads();
    mfma_mm<32, 128, SA, SA, SD, false, false>(Amat, t3T, b3, dts, tid);       // agg3
    __syncthreads();

    // ---- setup_b: convert u4 counts -> Amat + stage x2T (R1 free) ----
    {
        const float* xg = x2 + (size_t)g * NPG * F_IN;
        float4 xv0 = *(const float4*)&xg[tid * 4];
        float4 xv1 = *(const float4*)&xg[(1024 + tid) * 4];
        const int d = tid >> 3, q = tid & 7;
        const float dd = dinvB[d];
#pragma unroll
        for (int k = 0; k < 8; ++k) {
            const int w = q + k * 8;              // output u32 word (cols 2w, 2w+1)
            const int c0 = 2 * w;
            const unsigned int vin = cnt4[d * 16 + (c0 >> 3)];
            const int sh = (c0 & 7) << 2;
            int n0 = (vin >> sh) & 15;
            int n1 = (vin >> (sh + 4)) & 15;
            if (c0 == d) ++n0;
            if (c0 + 1 == d) ++n1;
            const f16 f0 = (f16)((float)n0 * dinvB[c0] * dd);
            const f16 f1 = (f16)((float)n1 * dinvB[c0 + 1] * dd);
            unsigned short u0 = __builtin_bit_cast(unsigned short, f0);
            unsigned short u1 = __builtin_bit_cast(unsigned short, f1);
            Acnt[d * 68 + w] = (unsigned int)u0 | ((unsigned int)u1 << 16);
        }
        {
            const int idx = tid * 4;
            const int n = idx >> 6, c = idx & 63;
            xT[(c + 0) * SA + n] = (f16)xv0.x;
            xT[(c + 1) * SA + n] = (f16)xv0.y;
            xT[(c + 2) * SA + n] = (f16)xv0.z;
            xT[(c + 3) * SA + n] = (f16)xv0.w;
        }
        {
            const int idx = (1024 + tid) * 4;
            const int n = idx >> 6, c = idx & 63;
            xT[(c + 0) * SA + n] = (f16)xv1.x;
            xT[(c + 1) * SA + n] = (f16)xv1.y;
            xT[(c + 2) * SA + n] = (f16)xv1.z;
            xT[(c + 3) * SA + n] = (f16)xv1.w;
        }
    }
    __syncthreads();

    // ---- side 1 layers ----
    mfma_mm<64, 128, SA, SA, SB, false, false>(Amat, xT, nullptr, out1, tid);  // agg1
    __syncthreads();
    mfma_mm<128, 64, SB, SB, SA, false, true>(out1, W1T, b1, h1, tid);         // mm1
    __syncthreads();
    mfma_mm<64, 128, SA, SA, SA, true, false>(h1, W2T, nullptr, t2T, tid);     // mm2 (T)
    __syncthreads();
    mfma_mm<64, 128, SA, SA, SB, false, true>(Amat, t2T, b2, h2, tid);         // agg2
    __syncthreads();
    mfma_mm<32, 64, SB, SB, SA, true, false>(h2, W3T, nullptr, t3T, tid);      // mm3 (T)
    __syncthreads();
    mfma_mm<32, 128, SA, SA, SD, false, false>(Amat, t3T, b3, dts + NPG * SD, tid); // agg3
    __syncthreads();

    // ================= post phase (dt1/dt2 in LDS) =================
    unsigned char* lhist = (unsigned char*)(pool + L_R4);   // [17][1040] u8
    float* pf   = (float*)(pool + L_R3);
    float* red  = pf;           // 32
    float* meanv= pf + 34;      // 64
    float* ctxv = pf + 98;      // 64
    float* ev   = pf + 162;     // 64
    float* feat = pf + 226;     // 32
    float* av   = pf + 290;     // 256
    float* pmean= pf + 546;     // 1024
    float* ptens= pf + 1570;    // 512
    int*   bins2= (int*)(pf + 2082); // 256
    const f16* d1 = dts;
    const f16* d2 = dts + NPG * SD;

    // ---- scores via MFMA: sc[n1][n2], K=32; 16 scores per thread ----
    const int col = lane & 15, gq = lane >> 4;
    const int strip = wv & 7, nh = wv >> 3;
    const int rowa = strip * 16 + col;
    f32x4 acc[4];
#pragma unroll
    for (int nt = 0; nt < 4; ++nt) acc[nt] = (f32x4){0.f, 0.f, 0.f, 0.f};
    {
        const f16x8 a = *(const f16x8*)&d1[rowa * SD + gq * 8];
#pragma unroll
        for (int nt = 0; nt < 4; ++nt) {
            const f16x8 b = *(const f16x8*)&d2[((nh * 4 + nt) * 16 + col) * SD + gq * 8];
            acc[nt] = __builtin_amdgcn_mfma_f32_16x16x32_f16(a, b, acc[nt], 0, 0, 0);
        }
    }
    // zero private hist (17*1040 bytes = 4420 u32) while scores are in flight
    for (int i = tid; i < 17 * LHS / 4; i += 1024) ((unsigned int*)lhist)[i] = 0u;
    // min/max (raw space)
    float lmin = acc[0][0], lmax = acc[0][0];
#pragma unroll
    for (int nt = 0; nt < 4; ++nt)
#pragma unroll
        for (int j = 0; j < 4; ++j) {
            lmin = fminf(lmin, acc[nt][j]);
            lmax = fmaxf(lmax, acc[nt][j]);
        }
    for (int off = 32; off; off >>= 1) {
        lmin = fminf(lmin, __shfl_down(lmin, off));
        lmax = fmaxf(lmax, __shfl_down(lmax, off));
    }
    if (lane == 0) { red[wv] = lmin; red[16 + wv] = lmax; }
    __syncthreads();

    // ---- phase A: all-thread lohi + histogram + attention pmean ----
    {
        float mn = red[0], mx = red[16];
        for (int w = 1; w < 16; ++w) { mn = fminf(mn, red[w]); mx = fmaxf(mx, red[16 + w]); }
        const float lo = sigmoidf(mn);
        const float hsc = (float)BINS / fmaxf(sigmoidf(mx) - lo, 1e-12f);
        unsigned char* lh = lhist + tid;
#pragma unroll
        for (int nt = 0; nt < 4; ++nt)
#pragma unroll
            for (int j = 0; j < 4; ++j) {
                const float v = sigmoidf(acc[nt][j]);
                int b = (int)((v - lo) * hsc);
                b = min(max(b, 0), BINS - 1);
                lh[b * LHS]++;
            }
    }
    {
        const int cc = tid & 63, chunk = tid >> 6;  // 16 chunks x 8 nodes
        const int side = cc >> 5, c = cc & 31;
        const f16* dp = dts + side * (NPG * SD);
        float s = 0.f;
        const int nbs = chunk * 8;
        for (int n = 0; n < 8; ++n) s += (float)dp[(nbs + n) * SD + c];
        pmean[chunk * 64 + cc] = s;
    }
    __syncthreads();

    // ---- phase B: hist reduce (tid<256) + meanv reduce (256<=tid<320) ----
    if (tid < 256) {
        const int b = tid & 15, chunk = tid >> 4;   // 16 chunks x 64 columns
        const unsigned char* row = lhist + b * LHS + chunk * 64;
        int s = 0;
#pragma unroll
        for (int i = 0; i < 4; ++i) {
            const uint4 v = *(const uint4*)(row + i * 16);
            unsigned int u;
            u = v.x; s += (u & 255) + ((u >> 8) & 255) + ((u >> 16) & 255) + (u >> 24);
            u = v.y; s += (u & 255) + ((u >> 8) & 255) + ((u >> 16) & 255) + (u >> 24);
            u = v.z; s += (u & 255) + ((u >> 8) & 255) + ((u >> 16) & 255) + (u >> 24);
            u = v.w; s += (u & 255) + ((u >> 8) & 255) + ((u >> 16) & 255) + (u >> 24);
        }
        bins2[chunk * 16 + b] = s;
    } else if (tid < 320) {
        const int t = tid - 256;
        float s = 0.f;
        for (int c = 0; c < 16; ++c) s += pmean[c * 64 + t];
        meanv[t] = s * (1.f / NPG);
    }
    __syncthreads();

    // ---- ctx (tid<64) ----
    if (tid < 64) {
        const int c = tid & 31;
        const float* mv = &meanv[(tid >> 5) * 32];
        float a = 0.f;
        for (int k = 0; k < F3; ++k) a += mv[k] * attW[k * F3 + c];
        ctxv[tid] = tanhf(a);
    }
    __syncthreads();

    // ---- av (tid<256) ----
    if (tid < 256) {
        const int n = tid & 127, side = tid >> 7;
        const f16* dp = dts + side * (NPG * SD);
        const float* cx = &ctxv[side * 32];
        float a = 0.f;
        for (int k = 0; k < F3; ++k) a += (float)dp[n * SD + k] * cx[k];
        av[tid] = sigmoidf(a);
    }
    __syncthreads();

    // ---- weighted pmean ----
    {
        const int cc = tid & 63, chunk = tid >> 6;
        const int side = cc >> 5, c = cc & 31;
        const f16* dp = dts + side * (NPG * SD);
        const float* a = &av[side * 128];
        float s = 0.f;
        const int nbs = chunk * 8;
        for (int n = 0; n < 8; ++n) s += a[nbs + n] * (float)dp[(nbs + n) * SD + c];
        pmean[chunk * 64 + cc] = s;
    }
    __syncthreads();

    // ---- ev reduce (tid<64) ----
    if (tid < 64) {
        float s = 0.f;
        for (int c = 0; c < 16; ++c) s += pmean[c * 64 + tid];
        ev[tid] = s;
    }
    __syncthreads();

    // ---- ptens (tid<512) + feat-bins (512<=tid<528) ----
    if (tid < 512) {
        const int k = tid & 15, i = tid >> 4;  // i in 0..31
        const float e1i = ev[i];
        float a = 0.f;
        for (int j = 0; j < F3; ++j) a += ev[32 + j] * tW[(i * F3 + j) * TN + k];
        ptens[i * 16 + k] = e1i * a;
    } else if (tid < 528) {
        const int b = tid - 512;
        int s = 0;
        for (int c = 0; c < 16; ++c) s += bins2[c * 16 + b];
        feat[TN + b] = (float)s * (1.f / (NPG * NPG));
    }
    __syncthreads();

    // ---- finale: wave 0 only (feat-tensor -> hv -> out, intra-wave ordered) ----
    if (wv == 0) {
        if (lane < TN) {
            float a = tbias[lane];
            for (int i = 0; i < 32; ++i) a += ptens[i * 16 + lane];
            for (int i = 0; i < F3; ++i) a += ev[i] * tblk[lane * 2 * F3 + i];
            for (int j = 0; j < F3; ++j) a += ev[32 + j] * tblk[lane * 2 * F3 + F3 + j];
            feat[lane] = fmaxf(a, 0.f);
        }
        asm volatile("s_waitcnt lgkmcnt(0)" ::: "memory");
        float hvj = 0.f;
        if (lane < 16) {
            float a = sb1[lane];
            for (int i = 0; i < TN + BINS; ++i) a += feat[i] * sW1[i * 16 + lane];
            hvj = fmaxf(a, 0.f) * sW2[lane];
        }
        for (int off = 8; off; off >>= 1) hvj += __shfl_down(hvj, off);
        if (lane == 0) outp[g] = sigmoidf(hvj + sb2[0]);
    }
}

// ---------------- launch ----------------
extern "C" void kernel_launch(void* const* d_in, const int* in_sizes, int n_in,
                              void* d_out, int out_size, void* d_ws, size_t ws_size,
                              hipStream_t stream) {
    const float* x1   = (const float*)d_in[0];
    const int*   ei1  = (const int*)d_in[1];
    const float* x2   = (const float*)d_in[3];
    const int*   ei2  = (const int*)d_in[4];
    const float* W1   = (const float*)d_in[6];
    const float* b1   = (const float*)d_in[7];
    const float* W2   = (const float*)d_in[8];
    const float* b2   = (const float*)d_in[9];
    const float* W3   = (const float*)d_in[10];
    const float* b3   = (const float*)d_in[11];
    const float* attW = (const float*)d_in[12];
    const float* tW   = (const float*)d_in[13];
    const float* tblk = (const float*)d_in[14];
    const float* tbias= (const float*)d_in[15];
    const float* sW1  = (const float*)d_in[16];
    const float* sb1  = (const float*)d_in[17];
    const float* sW2  = (const float*)d_in[18];
    const float* sb2  = (const float*)d_in[19];
    float* out = (float*)d_out;
    (void)in_sizes; (void)n_in; (void)out_size; (void)d_ws; (void)ws_size;

    genn_all<<<NGRAPH, 1024, 0, stream>>>(x1, ei1, x2, ei2,
                                          W1, b1, W2, b2, W3, b3,
                                          attW, tW, tblk, tbias,
                                          sW1, sb1, sW2, sb2, out);
}

// Round 18
// 32.077 us; speedup vs baseline: 1.0195x; 1.0195x over previous
//
#include <hip/hip_runtime.h>
#include <hip/hip_bf16.h>
#include <hip/hip_fp16.h>

// Problem constants (fixed by the reference harness)
#define N_NODES 32768
#define N_EDGES 524288
#define NGRAPH  256
#define NPG     128
#define EPG     2048     // edges per graph (DEG=16)
#define F_IN    64
#define F1      128
#define F2      64
#define F3      32
#define TN      16
#define BINS    16

typedef _Float16 f16;
typedef _Float16 f16x4 __attribute__((ext_vector_type(4)));
typedef _Float16 f16x8 __attribute__((ext_vector_type(8)));
typedef float    f32x4 __attribute__((ext_vector_type(4)));

__device__ __forceinline__ float sigmoidf(float x) { return 1.f / (1.f + expf(-x)); }

// ---- LDS pool (bytes), 149504 total -> 1 block/CU, 16 waves ----
#define L_A    0        // Acnt u32[128][68] == Amat f16[128][136] (per side)
#define L_R1   34816    // xT[64][136] -> h1[128][136] -> h2[128][72]
#define L_R2   69632    // W1T[128][72]
#define L_R3   88064    // out1[128][72] -> t2T[64][136] -> t3T[32][136] -> post smalls
#define L_R4   106496   // W2T[64][136] -> lhist u8[17][1040] (spills into R5)
#define L_R5   123904   // W3T[32][72]
#define L_DT   128512   // dt f16[2][128][40]; dt_b area doubles as cnt4_b+dinvB pre-agg3_b
#define L_DINV 148992   // dinv f32[128] (side a)
#define POOLB  149504

#define SA  136   // Amat / xT / h1 / W2T / t2T / t3T stride (f16)
#define SB  72    // out1 / W1T / h2 / W3T stride
#define SD  40    // dt stride
#define LHS 1040  // lhist stride (bytes), 16B-aligned

// ---- generic MFMA matmul over LDS f16 tiles; 16 waves = 8 M-strips x 2 N-halves ----
// out[r][c] (or out[c][r] if TRANS) = sum_k A[r][k]*B^T[c][k] (+bias[c]) (relu)
template<int N, int K, int AS, int BS, int OS, bool TRANS, bool RELU>
__device__ __forceinline__ void mfma_mm(const f16* __restrict__ A,
                                        const f16* __restrict__ B,
                                        const float* __restrict__ bias,
                                        f16* __restrict__ out, int tid) {
    const int w = tid >> 6, lane = tid & 63;
    const int col = lane & 15, g = lane >> 4;
    const int strip = w & 7, nh = w >> 3;
    const int rowa = strip * 16 + col;
    constexpr int NT = N / 16, KS = K / 32, NT2 = NT / 2;
    f32x4 acc[NT2];
#pragma unroll
    for (int nt = 0; nt < NT2; ++nt) {
        const float b = bias ? bias[(nh * NT2 + nt) * 16 + col] : 0.f;
        acc[nt] = (f32x4){b, b, b, b};
    }
#pragma unroll
    for (int ks = 0; ks < KS; ++ks) {
        const f16x8 a = *(const f16x8*)&A[rowa * AS + ks * 32 + g * 8];
#pragma unroll
        for (int nt = 0; nt < NT2; ++nt) {
            const f16x8 b = *(const f16x8*)&B[((nh * NT2 + nt) * 16 + col) * BS + ks * 32 + g * 8];
            acc[nt] = __builtin_amdgcn_mfma_f32_16x16x32_f16(a, b, acc[nt], 0, 0, 0);
        }
    }
#pragma unroll
    for (int nt = 0; nt < NT2; ++nt) {
        const int c = (nh * NT2 + nt) * 16 + col;
        if (TRANS) {
            f16x4 o;
#pragma unroll
            for (int j = 0; j < 4; ++j) {
                float v = acc[nt][j];
                if (RELU) v = fmaxf(v, 0.f);
                o[j] = (f16)v;
            }
            *(f16x4*)&out[c * OS + strip * 16 + g * 4] = o;
        } else {
#pragma unroll
            for (int j = 0; j < 4; ++j) {
                float v = acc[nt][j];
                if (RELU) v = fmaxf(v, 0.f);
                out[(strip * 16 + g * 4 + j) * OS + c] = (f16)v;
            }
        }
    }
}

// ---- the whole network: one block per graph pair, one dispatch, 1024 threads ----
__global__ __launch_bounds__(1024, 4) void genn_all(
    const float* __restrict__ x1, const int* __restrict__ ei1,
    const float* __restrict__ x2, const int* __restrict__ ei2,
    const float* __restrict__ W1, const float* __restrict__ b1,
    const float* __restrict__ W2, const float* __restrict__ b2,
    const float* __restrict__ W3, const float* __restrict__ b3,
    const float* __restrict__ attW, const float* __restrict__ tW,
    const float* __restrict__ tblk, const float* __restrict__ tbias,
    const float* __restrict__ sW1, const float* __restrict__ sb1,
    const float* __restrict__ sW2, const float* __restrict__ sb2,
    float* __restrict__ outp) {
    __shared__ __align__(16) char pool[POOLB];
    unsigned int* Acnt = (unsigned int*)(pool + L_A);
    f16*   Amat = (f16*)(pool + L_A);
    f16*   dts  = (f16*)(pool + L_DT);
    float* dinv = (float*)(pool + L_DINV);
    // side-b setup state parked in the dt_b region (dt_b written only at agg3_b)
    unsigned int* cnt4  = (unsigned int*)(pool + L_DT + 10240);   // u4 [128][128] = 8192 B
    float*        dinvB = (float*)(pool + L_DT + 18432);          // 512 B

    const int g = blockIdx.x;
    const int tid = threadIdx.x;
    const int wv = tid >> 6, lane = tid & 63;
    const int nb = g * NPG;

    // ---- P0: zero Acnt (2176 uint4) + cnt4 (512 uint4) ----
    for (int i = tid; i < 2176; i += 1024)
        ((uint4*)Acnt)[i] = make_uint4(0, 0, 0, 0);
    if (tid < 512) ((uint4*)cnt4)[tid] = make_uint4(0, 0, 0, 0);
    __syncthreads();

    // ---- P1: scatter BOTH sides + stage x1T + stage all W's ----
#pragma unroll
    for (int it = 0; it < 2; ++it) {
        const int e = it * 1024 + tid;
        const int d = ei1[N_EDGES + (size_t)g * EPG + e] - nb;
        const int s = ei1[(size_t)g * EPG + e] - nb;
        atomicAdd(&Acnt[d * 68 + (s >> 1)], 1u << ((s & 1) << 4));
    }
#pragma unroll
    for (int it = 0; it < 2; ++it) {
        const int e = it * 1024 + tid;
        const int d = ei2[N_EDGES + (size_t)g * EPG + e] - nb;
        const int s = ei2[(size_t)g * EPG + e] - nb;
        atomicAdd(&cnt4[d * 16 + (s >> 3)], 1u << ((s & 7) << 2));
    }
    {
        const float* xg = x1 + (size_t)g * NPG * F_IN;
        f16* xT = (f16*)(pool + L_R1);
#pragma unroll
        for (int it = 0; it < 2; ++it) {
            const int idx = (it * 1024 + tid) * 4;
            const float4 v = *(const float4*)&xg[idx];
            const int n = idx >> 6, c = idx & 63;
            xT[(c + 0) * SA + n] = (f16)v.x;
            xT[(c + 1) * SA + n] = (f16)v.y;
            xT[(c + 2) * SA + n] = (f16)v.z;
            xT[(c + 3) * SA + n] = (f16)v.w;
        }
        f16* W1T = (f16*)(pool + L_R2);
        for (int i = tid; i < F_IN * F1; i += 1024)
            W1T[(i & 127) * SB + (i >> 7)] = (f16)W1[i];
        f16* W2T = (f16*)(pool + L_R4);
        for (int i = tid; i < F1 * F2; i += 1024)
            W2T[(i & 63) * SA + (i >> 6)] = (f16)W2[i];
        f16* W3T = (f16*)(pool + L_R5);
        for (int i = tid; i < F2 * F3; i += 1024)
            W3T[(i & 31) * SB + (i >> 5)] = (f16)W3[i];
    }
    __syncthreads();

    // ---- P2: rowsums for BOTH sides ----
    if (tid < 512) {
        const int d = tid >> 2, q = tid & 3;
        unsigned int s = 0;
        const unsigned int* rp = &Acnt[d * 68 + q * 17];
        for (int j = 0; j < 17; ++j) {
            const unsigned int v = rp[j];
            s += (v & 0xffffu) + (v >> 16);
        }
        s += __shfl_down((int)s, 2);
        s += __shfl_down((int)s, 1);
        if (q == 0) dinv[d] = rsqrtf((float)s + 1.0f);
    } else {
        const int t = tid - 512;
        const int d = t >> 2, q = t & 3;
        unsigned int s = 0;
#pragma unroll
        for (int k = 0; k < 4; ++k) {
            const unsigned int v = cnt4[d * 16 + q * 4 + k];
            const unsigned int v2 = (v & 0x0F0F0F0Fu) + ((v >> 4) & 0x0F0F0F0Fu);
            s += (v2 & 0xFFu) + ((v2 >> 8) & 0xFFu) + ((v2 >> 16) & 0xFFu) + (v2 >> 24);
        }
        s += __shfl_down((int)s, 2);
        s += __shfl_down((int)s, 1);
        if (q == 0) dinvB[d] = rsqrtf((float)s + 1.0f);
    }
    __syncthreads();

    // ---- P3: convert side-a counts -> Amat f16 in place (+ self loop) ----
    for (int i = tid; i < 8704; i += 1024) {
        const int d = i / 68, w = i % 68;
        const unsigned int v = Acnt[i];
        const int s0 = 2 * w, s1 = 2 * w + 1;
        int c0 = v & 0xffffu, c1 = v >> 16;
        if (s0 == d) ++c0;
        if (s1 == d) ++c1;
        const float dd = dinv[d];
        const f16 f0 = (f16)((float)c0 * dinv[s0 & 127] * dd);
        const f16 f1 = (f16)((float)c1 * dinv[s1 & 127] * dd);
        unsigned short u0 = __builtin_bit_cast(unsigned short, f0);
        unsigned short u1 = __builtin_bit_cast(unsigned short, f1);
        Acnt[i] = (unsigned int)u0 | ((unsigned int)u1 << 16);
    }
    __syncthreads();

    // ---- region aliases ----
    f16* xT   = (f16*)(pool + L_R1);
    f16* h1   = (f16*)(pool + L_R1);
    f16* h2   = (f16*)(pool + L_R1);   // reuses R1 (h1 dead after mm2)
    f16* W1T  = (f16*)(pool + L_R2);
    f16* out1 = (f16*)(pool + L_R3);
    f16* t2T  = (f16*)(pool + L_R3);
    f16* t3T  = (f16*)(pool + L_R3);
    f16* W2T  = (f16*)(pool + L_R4);
    f16* W3T  = (f16*)(pool + L_R5);

    // ---- side 0 layers ----
    mfma_mm<64, 128, SA, SA, SB, false, false>(Amat, xT, nullptr, out1, tid);  // agg1
    __syncthreads();
    mfma_mm<128, 64, SB, SB, SA, false, true>(out1, W1T, b1, h1, tid);         // mm1
    __syncthreads();
    mfma_mm<64, 128, SA, SA, SA, true, false>(h1, W2T, nullptr, t2T, tid);     // mm2 (T)
    __syncthreads();
    mfma_mm<64, 128, SA, SA, SB, false, true>(Amat, t2T, b2, h2, tid);         // agg2
    __syncthreads();
    mfma_mm<32, 64, SB, SB, SA, true, false>(h2, W3T, nullptr, t3T, tid);      // mm3 (T)
    __syncthreads();
    mfma_mm<32, 128, SA, SA, SD, false, false>(Amat, t3T, b3, dts, tid);       // agg3
    __syncthreads();

    // ---- setup_b: convert u4 counts -> Amat + stage x2T (R1 free) ----
    {
        const float* xg = x2 + (size_t)g * NPG * F_IN;
        float4 xv0 = *(const float4*)&xg[tid * 4];
        float4 xv1 = *(const float4*)&xg[(1024 + tid) * 4];
        const int d = tid >> 3, q = tid & 7;
        const float dd = dinvB[d];
#pragma unroll
        for (int k = 0; k < 8; ++k) {
            const int w = q + k * 8;              // output u32 word (cols 2w, 2w+1)
            const int c0 = 2 * w;
            const unsigned int vin = cnt4[d * 16 + (c0 >> 3)];
            const int sh = (c0 & 7) << 2;
            int n0 = (vin >> sh) & 15;
            int n1 = (vin >> (sh + 4)) & 15;
            if (c0 == d) ++n0;
            if (c0 + 1 == d) ++n1;
            const f16 f0 = (f16)((float)n0 * dinvB[c0] * dd);
            const f16 f1 = (f16)((float)n1 * dinvB[c0 + 1] * dd);
            unsigned short u0 = __builtin_bit_cast(unsigned short, f0);
            unsigned short u1 = __builtin_bit_cast(unsigned short, f1);
            Acnt[d * 68 + w] = (unsigned int)u0 | ((unsigned int)u1 << 16);
        }
        {
            const int idx = tid * 4;
            const int n = idx >> 6, c = idx & 63;
            xT[(c + 0) * SA + n] = (f16)xv0.x;
            xT[(c + 1) * SA + n] = (f16)xv0.y;
            xT[(c + 2) * SA + n] = (f16)xv0.z;
            xT[(c + 3) * SA + n] = (f16)xv0.w;
        }
        {
            const int idx = (1024 + tid) * 4;
            const int n = idx >> 6, c = idx & 63;
            xT[(c + 0) * SA + n] = (f16)xv1.x;
            xT[(c + 1) * SA + n] = (f16)xv1.y;
            xT[(c + 2) * SA + n] = (f16)xv1.z;
            xT[(c + 3) * SA + n] = (f16)xv1.w;
        }
    }
    __syncthreads();

    // ---- side 1 layers ----
    mfma_mm<64, 128, SA, SA, SB, false, false>(Amat, xT, nullptr, out1, tid);  // agg1
    __syncthreads();
    mfma_mm<128, 64, SB, SB, SA, false, true>(out1, W1T, b1, h1, tid);         // mm1
    __syncthreads();
    mfma_mm<64, 128, SA, SA, SA, true, false>(h1, W2T, nullptr, t2T, tid);     // mm2 (T)
    __syncthreads();
    mfma_mm<64, 128, SA, SA, SB, false, true>(Amat, t2T, b2, h2, tid);         // agg2
    __syncthreads();
    mfma_mm<32, 64, SB, SB, SA, true, false>(h2, W3T, nullptr, t3T, tid);      // mm3 (T)
    __syncthreads();
    mfma_mm<32, 128, SA, SA, SD, false, false>(Amat, t3T, b3, dts + NPG * SD, tid); // agg3
    __syncthreads();

    // ================= post phase (dt1/dt2 in LDS) =================
    unsigned char* lhist = (unsigned char*)(pool + L_R4);   // [17][1040] u8
    float* pf   = (float*)(pool + L_R3);
    float* red  = pf;           // 32
    float* lohi = pf + 32;      // 2 (lo, scale)
    float* meanv= pf + 34;      // 64
    float* ctxv = pf + 98;      // 64
    float* ev   = pf + 162;     // 64
    float* feat = pf + 226;     // 32
    float* hv   = pf + 258;     // 16
    float* av   = pf + 290;     // 256
    float* pmean= pf + 546;     // 1024
    float* ptens= pf + 1570;    // 512
    int*   bins2= (int*)(pf + 2082); // 256
    const f16* d1 = dts;
    const f16* d2 = dts + NPG * SD;

    // ---- scores via MFMA: sc[n1][n2], K=32; 16 scores per thread ----
    const int col = lane & 15, gq = lane >> 4;
    const int strip = wv & 7, nh = wv >> 3;
    const int rowa = strip * 16 + col;
    f32x4 acc[4];
#pragma unroll
    for (int nt = 0; nt < 4; ++nt) acc[nt] = (f32x4){0.f, 0.f, 0.f, 0.f};
    {
        const f16x8 a = *(const f16x8*)&d1[rowa * SD + gq * 8];
#pragma unroll
        for (int nt = 0; nt < 4; ++nt) {
            const f16x8 b = *(const f16x8*)&d2[((nh * 4 + nt) * 16 + col) * SD + gq * 8];
            acc[nt] = __builtin_amdgcn_mfma_f32_16x16x32_f16(a, b, acc[nt], 0, 0, 0);
        }
    }
    // zero private hist (17*1040 bytes = 4420 u32) while scores are in flight
    for (int i = tid; i < 17 * LHS / 4; i += 1024) ((unsigned int*)lhist)[i] = 0u;
    // min/max (raw space)
    float lmin = acc[0][0], lmax = acc[0][0];
#pragma unroll
    for (int nt = 0; nt < 4; ++nt)
#pragma unroll
        for (int j = 0; j < 4; ++j) {
            lmin = fminf(lmin, acc[nt][j]);
            lmax = fmaxf(lmax, acc[nt][j]);
        }
    for (int off = 32; off; off >>= 1) {
        lmin = fminf(lmin, __shfl_down(lmin, off));
        lmax = fmaxf(lmax, __shfl_down(lmax, off));
    }
    if (lane == 0) { red[wv] = lmin; red[16 + wv] = lmax; }
    __syncthreads();
    if (tid == 0) {
        float mn = red[0], mx = red[16];
        for (int w = 1; w < 16; ++w) { mn = fminf(mn, red[w]); mx = fmaxf(mx, red[16 + w]); }
        const float los = sigmoidf(mn);
        const float den = fmaxf(sigmoidf(mx) - los, 1e-12f);
        lohi[0] = los;
        lohi[1] = (float)BINS / den;
    }
    __syncthreads();

    // ---- histogram: direct sigmoid binning into transposed private counters ----
    {
        const float lo = lohi[0], sc = lohi[1];
        unsigned char* lh = lhist + tid;
#pragma unroll
        for (int nt = 0; nt < 4; ++nt)
#pragma unroll
            for (int j = 0; j < 4; ++j) {
                const float v = sigmoidf(acc[nt][j]);
                int b = (int)((v - lo) * sc);
                b = min(max(b, 0), BINS - 1);
                lh[b * LHS]++;
            }
    }
    __syncthreads();
    if (tid < 256) {
        const int b = tid & 15, chunk = tid >> 4;   // 16 chunks x 64 columns
        const unsigned char* row = lhist + b * LHS + chunk * 64;
        int s = 0;
#pragma unroll
        for (int i = 0; i < 4; ++i) {
            const uint4 v = *(const uint4*)(row + i * 16);
            unsigned int u;
            u = v.x; s += (u & 255) + ((u >> 8) & 255) + ((u >> 16) & 255) + (u >> 24);
            u = v.y; s += (u & 255) + ((u >> 8) & 255) + ((u >> 16) & 255) + (u >> 24);
            u = v.z; s += (u & 255) + ((u >> 8) & 255) + ((u >> 16) & 255) + (u >> 24);
            u = v.w; s += (u & 255) + ((u >> 8) & 255) + ((u >> 16) & 255) + (u >> 24);
        }
        bins2[chunk * 16 + b] = s;
    }
    __syncthreads();

    // ---- attention pooling (dt is [n][c] stride SD) ----
    {
        const int cc = tid & 63, chunk = tid >> 6;  // 16 chunks x 8 nodes
        const int side = cc >> 5, c = cc & 31;
        const f16* dp = dts + side * (NPG * SD);
        float s = 0.f;
        const int nbs = chunk * 8;
        for (int n = 0; n < 8; ++n) s += (float)dp[(nbs + n) * SD + c];
        pmean[chunk * 64 + cc] = s;
    }
    __syncthreads();
    if (tid < 64) {
        float s = 0.f;
        for (int c = 0; c < 16; ++c) s += pmean[c * 64 + tid];
        meanv[tid] = s * (1.f / NPG);
    }
    __syncthreads();
    if (tid < 64) {
        const int c = tid & 31;
        const float* mv = &meanv[(tid >> 5) * 32];
        float a = 0.f;
        for (int k = 0; k < F3; ++k) a += mv[k] * attW[k * F3 + c];
        ctxv[tid] = tanhf(a);
    }
    __syncthreads();
    if (tid < 256) {
        const int n = tid & 127, side = tid >> 7;
        const f16* dp = dts + side * (NPG * SD);
        const float* cx = &ctxv[side * 32];
        float a = 0.f;
        for (int k = 0; k < F3; ++k) a += (float)dp[n * SD + k] * cx[k];
        av[tid] = sigmoidf(a);
    }
    __syncthreads();
    {
        const int cc = tid & 63, chunk = tid >> 6;
        const int side = cc >> 5, c = cc & 31;
        const f16* dp = dts + side * (NPG * SD);
        const float* a = &av[side * 128];
        float s = 0.f;
        const int nbs = chunk * 8;
        for (int n = 0; n < 8; ++n) s += a[nbs + n] * (float)dp[(nbs + n) * SD + c];
        pmean[chunk * 64 + cc] = s;
    }
    __syncthreads();
    if (tid < 64) {
        float s = 0.f;
        for (int c = 0; c < 16; ++c) s += pmean[c * 64 + tid];
        ev[tid] = s;
    }
    __syncthreads();

    // ---- tensor network ----
    if (tid < 512) {
        const int k = tid & 15, i = tid >> 4;  // i in 0..31
        const float e1i = ev[i];
        float a = 0.f;
        for (int j = 0; j < F3; ++j) a += ev[32 + j] * tW[(i * F3 + j) * TN + k];
        ptens[i * 16 + k] = e1i * a;
    }
    __syncthreads();
    if (tid < TN) {
        float a = tbias[tid];
        for (int i = 0; i < 32; ++i) a += ptens[i * 16 + tid];
        for (int i = 0; i < F3; ++i) a += ev[i] * tblk[tid * 2 * F3 + i];
        for (int j = 0; j < F3; ++j) a += ev[32 + j] * tblk[tid * 2 * F3 + F3 + j];
        feat[tid] = fmaxf(a, 0.f);
    } else if (tid < TN + BINS) {
        const int b = tid - TN;
        int s = 0;
        for (int c = 0; c < 16; ++c) s += bins2[c * 16 + b];
        feat[tid] = (float)s * (1.f / (NPG * NPG));
    }
    __syncthreads();
    if (tid < 16) {
        float a = sb1[tid];
        for (int i = 0; i < TN + BINS; ++i) a += feat[i] * sW1[i * 16 + tid];
        hv[tid] = fmaxf(a, 0.f);
    }
    __syncthreads();
    if (tid == 0) {
        float a = sb2[0];
        for (int j = 0; j < 16; ++j) a += hv[j] * sW2[j];
        outp[g] = sigmoidf(a);
    }
}

// ---------------- launch ----------------
extern "C" void kernel_launch(void* const* d_in, const int* in_sizes, int n_in,
                              void* d_out, int out_size, void* d_ws, size_t ws_size,
                              hipStream_t stream) {
    const float* x1   = (const float*)d_in[0];
    const int*   ei1  = (const int*)d_in[1];
    const float* x2   = (const float*)d_in[3];
    const int*   ei2  = (const int*)d_in[4];
    const float* W1   = (const float*)d_in[6];
    const float* b1   = (const float*)d_in[7];
    const float* W2   = (const float*)d_in[8];
    const float* b2   = (const float*)d_in[9];
    const float* W3   = (const float*)d_in[10];
    const float* b3   = (const float*)d_in[11];
    const float* attW = (const float*)d_in[12];
    const float* tW   = (const float*)d_in[13];
    const float* tblk = (const float*)d_in[14];
    const float* tbias= (const float*)d_in[15];
    const float* sW1  = (const float*)d_in[16];
    const float* sb1  = (const float*)d_in[17];
    const float* sW2  = (const float*)d_in[18];
    const float* sb2  = (const float*)d_in[19];
    float* out = (float*)d_out;
    (void)in_sizes; (void)n_in; (void)out_size; (void)d_ws; (void)ws_size;

    genn_all<<<NGRAPH, 1024, 0, stream>>>(x1, ei1, x2, ei2,
                                          W1, b1, W2, b2, W3, b3,
                                          attW, tW, tblk, tbias,
                                          sW1, sb1, sW2, sb2, out);
}